// Round 17
// baseline (271.737 us; speedup 1.0000x reference)
//
#include <hip/hip_runtime.h>
#include <math.h>

// Problem constants: B=512, C=50000, D=256.
#define D_DIM 256
#define TM 128
#define TN 128
#define BK 32     // K-step depth (bf16); 8 K-iterations
#define NBP 392   // padded partial stride (NB=391)
#define CBPR 7    // compress blocks per row (7*4 waves*2048 cols = 57344 >= 50000)
#define CBLKS (CBPR * 512)   // 3584 compress-role blocks

typedef __attribute__((ext_vector_type(8))) short short8;
typedef __attribute__((ext_vector_type(4))) float floatx4;
typedef __attribute__((ext_vector_type(4))) int intx4;
typedef unsigned long long u64;

__device__ __forceinline__ unsigned short f2bf(float f) {
    unsigned int u = __float_as_uint(f);
    u += 0x7FFFu + ((u >> 16) & 1u);   // round-to-nearest-even
    return (unsigned short)(u >> 16);
}

// ---- kernel 1: fused label-compress + norms/bf16-convert/loadedmask (R13-exact) -----
// NT loads on read-once streams: the R13 win (263->254.6). R16's role-interleave
// REGRESSED (prep 58->69, occ 43->31) and is reverted.
__global__ __launch_bounds__(256) void prep_compress(
    const float* __restrict__ V, const float* __restrict__ T,
    const int* __restrict__ label, const int* __restrict__ ids,
    u64* __restrict__ loadedmask, u64* __restrict__ posmask,
    unsigned short* __restrict__ Vb, unsigned short* __restrict__ Tb,
    float* __restrict__ gaccum, unsigned int* __restrict__ gcount,
    int B, int C, int n_loaded, int WPR) {
    const int bid = blockIdx.x;
    const int tid = threadIdx.x;
    const int lane = tid & 63;

    if (bid < CBLKS) {   // ---- compress role: 102 MB label stream -> 3.2 MB raw posmask
        int row = bid / CBPR;
        int sub = bid - row * CBPR;
        int wl  = tid >> 6;
        int w0col = (sub * 4 + wl) * 2048;     // this wave's 2048-col window
        if (w0col >= C) return;
        const int* lp = label + (size_t)row * C;
        intx4 lo[4], hi[4];
        #pragma unroll
        for (int r = 0; r < 4; ++r) {          // 8 x 16B nt loads in flight
            int c0 = w0col + r * 512 + lane * 8;
            if (c0 < C) {                      // C%8==0: full 8-col chunk valid
                lo[r] = __builtin_nontemporal_load((const intx4*)(lp + c0));
                hi[r] = __builtin_nontemporal_load((const intx4*)(lp + c0 + 4));
            } else {
                lo[r] = (intx4)0;
                hi[r] = (intx4)0;
            }
        }
        #pragma unroll
        for (int r = 0; r < 4; ++r) {
            unsigned int by =
                (lo[r][0] ? 1u : 0u) | (lo[r][1] ? 2u : 0u) |
                (lo[r][2] ? 4u : 0u) | (lo[r][3] ? 8u : 0u) |
                (hi[r][0] ? 16u : 0u) | (hi[r][1] ? 32u : 0u) |
                (hi[r][2] ? 64u : 0u) | (hi[r][3] ? 128u : 0u);
            u64 wv = (u64)by << (8 * (lane & 7));
            wv |= __shfl_xor(wv, 1);           // OR-butterfly across 8-lane group
            wv |= __shfl_xor(wv, 2);
            wv |= __shfl_xor(wv, 4);
            if ((lane & 7) == 0) {
                int wc = ((w0col + r * 512) >> 6) + (lane >> 3);
                if (wc < WPR) posmask[(size_t)row * WPR + wc] = wv;
            }
        }
        return;
    }

    // ---- prep role: loadedmask (binary search over sorted ids) + normalize -> bf16
    int ptid = (bid - CBLKS) * 256 + tid;
    if (ptid == 0) { *gcount = 0u; *gaccum = 0.f; }   // zero reduce scratch each call
    if (ptid < WPR) {
        int base = ptid << 6;
        int lo = 0, hi = n_loaded;
        while (lo < hi) { int mid = (lo + hi) >> 1; if (ids[mid] < base) lo = mid + 1; else hi = mid; }
        u64 m = 0;
        for (int i = lo; i < n_loaded; ++i) {
            int v = ids[i]; if (v >= base + 64) break;
            m |= 1ull << (v - base);
        }
        loadedmask[ptid] = m;
    }
    int wave = ptid >> 6;
    if (wave >= B + C) return;   // whole wave uniform
    bool isV = wave < B;
    const float* src = isV ? (V + (size_t)wave * D_DIM)
                           : (T + (size_t)(wave - B) * D_DIM);
    floatx4 x = __builtin_nontemporal_load(((const floatx4*)src) + lane);
    float ss = x[0] * x[0] + x[1] * x[1] + x[2] * x[2] + x[3] * x[3];
    #pragma unroll
    for (int off = 32; off > 0; off >>= 1) ss += __shfl_xor(ss, off);
    float nrm = sqrtf(ss);
    float s = isV ? (1.0f / nrm) : (1.0f / (1e-6f + nrm));   // eps on text norms only
    ushort4 o;
    o.x = f2bf(x[0] * s); o.y = f2bf(x[1] * s);
    o.z = f2bf(x[2] * s); o.w = f2bf(x[3] * s);
    unsigned short* dst = isV ? (Vb + (size_t)wave * D_DIM)
                              : (Tb + (size_t)(wave - B) * D_DIM);
    ((ushort4*)dst)[lane] = o;   // cached store: Vb/Tb are re-read by gemm
}

// ---- kernel 2 (R17): ZERO-LDS gemm -- direct-from-L2 register fragments -------------
// Guide Common-mistake #7: never LDS-stage data that L2-fits. Vb = 256KB (every L2);
// after the R15 XCD swizzle each XCD's Tb slice ~ 1.6MB (fits its 4MB L2). LDS staging
// forced a vmcnt-draining __syncthreads per K-step -- the latency exposure every
// pipelining attempt (R3/R9/R11) failed to remove. Fragments are loaded straight from
// global per-lane (each instr touches the same 16 cache lines a staged load would);
// NO barriers in the K-loop, so the compiler pipelines loads across steps freely.
// __launch_bounds__(256,3) caps VGPR ~168 to protect occupancy.
__global__ __launch_bounds__(256, 3) void gemm_fused(
    const unsigned short* __restrict__ Vb, const unsigned short* __restrict__ Tb,
    const u64* __restrict__ posmask, const u64* __restrict__ loadedmask,
    float* __restrict__ denomP, float* __restrict__ posP, int C, int WPR) {
    __shared__ float sDen[TM], sPos[TM];

    const int tid  = threadIdx.x;
    const int lane = tid & 63;
    const int w    = tid >> 6;

    // bijective XCD-chunk swizzle (R15 win): id%8 = XCD; contiguous wgid chunk per XCD
    const int nwg  = gridDim.x;
    const int id   = blockIdx.x;
    const int q    = nwg >> 3, r = nwg & 7;
    const int xcd  = id & 7, slot = id >> 3;
    const int wgid = (xcd < r) ? xcd * (q + 1) + slot
                               : r * (q + 1) + (xcd - r) * q + slot;
    const int m0 = (wgid & 3) * TM;     // m fastest within the chunk
    const int nb = wgid >> 2;           // n-block index
    const int n0 = nb * TN;

    if (tid < TM) { sDen[tid] = 0.f; sPos[tid] = 0.f; }

    // ---- compute mapping: 2x2 waves, each 64x64 via 4x4 frags of 16x16x32
    const int wm = (w >> 1) * 64;
    const int wn = (w & 1) * 64;
    const int fr = lane & 15;
    const int quad = lane >> 4;

    // per-lane direct operand pointers. A frag mi: row m0+wm+mi*16+fr, k-chunk quad.
    const unsigned short* pA = Vb + (size_t)(m0 + wm + fr) * D_DIM + quad * 8;
    const unsigned short* pB[4];
    #pragma unroll
    for (int ni = 0; ni < 4; ni++) {
        int rr = n0 + wn + ni * 16 + fr;
        if (rr >= C) rr = C - 1;        // OOB rows: valid address, masked in epilogue
        pB[ni] = Tb + (size_t)rr * D_DIM + quad * 8;
    }

    floatx4 acc[4][4];
    #pragma unroll
    for (int mi = 0; mi < 4; mi++)
        #pragma unroll
        for (int ni = 0; ni < 4; ni++) acc[mi][ni] = (floatx4)0.f;

    #pragma unroll
    for (int kt = 0; kt < D_DIM / BK; ++kt) {
        const int kb = kt * BK;
        short8 af[4], bf[4];
        #pragma unroll
        for (int mi = 0; mi < 4; mi++)
            af[mi] = *(const short8*)(pA + (size_t)mi * 16 * D_DIM + kb);
        #pragma unroll
        for (int ni = 0; ni < 4; ni++)
            bf[ni] = *(const short8*)(pB[ni] + kb);
        #pragma unroll
        for (int mi = 0; mi < 4; mi++)
            #pragma unroll
            for (int ni = 0; ni < 4; ni++)
                acc[mi][ni] = __builtin_amdgcn_mfma_f32_16x16x32_bf16(
                    af[mi], bf[ni], acc[mi][ni], 0, 0, 0);
    }

    __syncthreads();   // sDen/sPos init visible before epilogue atomics

    // ---- epilogue: D layout row = quad*4 + reg, col = lane&15 per 16x16 frag.
    const int wcol = (n0 + wn) >> 6;          // this wave's 64-col mask word
    const u64 loadedw = loadedmask[wcol];
    #pragma unroll
    for (int mi = 0; mi < 4; mi++) {
        #pragma unroll
        for (int i = 0; i < 4; i++) {
            const int mloc = wm + mi * 16 + quad * 4 + i;
            const u64 praw = posmask[(size_t)(m0 + mloc) * WPR + wcol];  // L2/L3-hit
            const u64 posw = praw & loadedw;
            const u64 negw = loadedw & ~praw;
            float den = 0.f, pos = 0.f;
            #pragma unroll
            for (int ni = 0; ni < 4; ni++) {
                const float s = acc[mi][ni][i];
                const int bit = ni * 16 + fr;
                if ((negw >> bit) & 1) den += __expf(s);
                if ((posw >> bit) & 1) pos += s;
            }
            #pragma unroll
            for (int off = 8; off >= 1; off >>= 1) {   // reduce 16-lane quad row
                den += __shfl_xor(den, off);
                pos += __shfl_xor(pos, off);
            }
            if (fr == 0) {
                if (den != 0.f) atomicAdd(&sDen[mloc], den);
                if (pos != 0.f) atomicAdd(&sPos[mloc], pos);
            }
        }
    }
    __syncthreads();
    if (tid < TM) {   // row-major partials: [row][n-block] for coalesced reduce
        denomP[(size_t)(m0 + tid) * NBP + nb] = sDen[tid];
        posP[(size_t)(m0 + tid) * NBP + nb]   = sPos[tid];
    }
}

// ---- kernel 3: reduce rows + last-block computes the final mean (R5-exact) ----------
__global__ void reduce_rows(const float* __restrict__ denomP, const float* __restrict__ posP,
                            const u64* __restrict__ posmask, const u64* __restrict__ loadedmask,
                            float* __restrict__ gaccum, unsigned int* __restrict__ gcount,
                            float* __restrict__ out, int B, int NB, int WPR) {
    __shared__ float bsum[4];
    int wv   = threadIdx.x >> 6;
    int row  = blockIdx.x * 4 + wv;
    int lane = threadIdx.x & 63;
    float den = 0.f, pos = 0.f;
    int cnt = 0;
    if (row < B) {
        for (int bn = lane; bn < NB; bn += 64) {   // contiguous within row: coalesced
            den += denomP[(size_t)row * NBP + bn];
            pos += posP[(size_t)row * NBP + bn];
        }
        for (int j = lane; j < WPR; j += 64)
            cnt += __popcll(posmask[(size_t)row * WPR + j] & loadedmask[j]);
        #pragma unroll
        for (int off = 32; off > 0; off >>= 1) {
            den += __shfl_xor(den, off);
            pos += __shfl_xor(pos, off);
            cnt += __shfl_xor(cnt, off);
        }
    }
    if (lane == 0) bsum[wv] = (row < B) ? (logf(den) - pos / (float)cnt) : 0.f;
    __syncthreads();
    if (threadIdx.x == 0) {
        float s = bsum[0] + bsum[1] + bsum[2] + bsum[3];
        atomicAdd(gaccum, s);            // 128 ops total: contention negligible
        __threadfence();
        unsigned int old = atomicAdd(gcount, 1u);
        if (old == gridDim.x - 1) {      // last block: all adds complete & visible
            float tot = atomicAdd(gaccum, 0.0f);   // atomic read-back
            out[0] = tot / (float)B;
        }
    }
}

extern "C" void kernel_launch(void* const* d_in, const int* in_sizes, int n_in,
                              void* d_out, int out_size, void* d_ws, size_t ws_size,
                              hipStream_t stream) {
    const float* V     = (const float*)d_in[0];
    const float* T     = (const float*)d_in[1];
    const int*   label = (const int*)d_in[2];
    const int*   ids   = (const int*)d_in[3];
    int B = in_sizes[0] / D_DIM;   // 512
    int C = in_sizes[1] / D_DIM;   // 50000
    int n_loaded = in_sizes[3];    // 40000
    int WPR = (C + 63) >> 6;       // mask words per row (782)
    int NB  = (C + TN - 1) / TN;   // n-blocks (391)

    // ws layout (bytes):
    //   0        : gaccum [1 f], gcount [1 u32]     (pad to 2048)
    //   2048     : loadedmask [782 u64]             (ends 8304; pad to 8320)
    //   8320     : posmask [512*782 u64]            (3,203,072 -> ends 3,211,392)
    //   3211392  : Vb [512*256 bf16]                (262,144 -> ends 3,473,536)
    //   3473536  : Tb [50000*256 bf16]              (25.6 MB -> ends 29,073,536)
    //   29073536 : denomP [512*NBP f]               (802,816 -> ends 29,876,352)
    //   29876352 : posP                             (ends 30,679,168)
    char* ws = (char*)d_ws;
    float*        gaccum = (float*)(ws + 0);
    unsigned int* gcount = (unsigned int*)(ws + 8);
    u64*   loadedmask = (u64*)(ws + 2048);
    u64*   posmask    = (u64*)(ws + 8320);
    unsigned short* Vb = (unsigned short*)(ws + 3211392);
    unsigned short* Tb = (unsigned short*)(ws + 3473536);
    float* denomP  = (float*)(ws + 29073536);
    float* posP    = (float*)(ws + 29876352);

    int prep_blocks = ((B + C) * 64 + 255) / 256;    // 12628
    prep_compress<<<CBLKS + prep_blocks, 256, 0, stream>>>(
        V, T, label, ids, loadedmask, posmask, Vb, Tb, gaccum, gcount,
        B, C, n_loaded, WPR);

    int gemm_blocks = (B / TM) * NB;   // 1564; 1D grid for the XCD swizzle
    gemm_fused<<<gemm_blocks, 256, 0, stream>>>(Vb, Tb, posmask, loadedmask,
                                                denomP, posP, C, WPR);

    reduce_rows<<<(B + 3) / 4, 256, 0, stream>>>(denomP, posP, posmask, loadedmask,
                                                 gaccum, gcount, (float*)d_out, B, NB, WPR);
}

// Round 18
// 244.765 us; speedup vs baseline: 1.1102x; 1.1102x over previous
//
#include <hip/hip_runtime.h>
#include <math.h>

// Problem constants: B=512, C=50000, D=256.
#define D_DIM 256
#define TM 128
#define TN 128
#define BK 32     // K-tile depth (bf16); 8 K-iterations
#define NBP 392   // padded partial stride (NB=391)
#define CBPR 7    // compress blocks per row (7*4 waves*2048 cols = 57344 >= 50000)
#define CBLKS (CBPR * 512)   // 3584 compress-role blocks

typedef __attribute__((ext_vector_type(8))) short short8;
typedef __attribute__((ext_vector_type(4))) float floatx4;
typedef __attribute__((ext_vector_type(4))) int intx4;
typedef unsigned long long u64;

__device__ __forceinline__ unsigned short f2bf(float f) {
    unsigned int u = __float_as_uint(f);
    u += 0x7FFFu + ((u >> 16) & 1u);   // round-to-nearest-even
    return (unsigned short)(u >> 16);
}

// async global->LDS 16B: lane l's 16B lands at ldsbase + l*16 (wave-uniform base)
__device__ __forceinline__ void gload16(const void* g, void* lds) {
    __builtin_amdgcn_global_load_lds(
        (const __attribute__((address_space(1))) unsigned int*)g,
        (__attribute__((address_space(3))) unsigned int*)lds, 16, 0, 0);
}

// ---- kernel 1: fused label-compress + norms/bf16-convert/loadedmask (R13-exact) -----
// NT loads on read-once streams: the R13 win (263->254.6). R16 interleave regressed.
__global__ __launch_bounds__(256) void prep_compress(
    const float* __restrict__ V, const float* __restrict__ T,
    const int* __restrict__ label, const int* __restrict__ ids,
    u64* __restrict__ loadedmask, u64* __restrict__ posmask,
    unsigned short* __restrict__ Vb, unsigned short* __restrict__ Tb,
    float* __restrict__ gaccum, unsigned int* __restrict__ gcount,
    int B, int C, int n_loaded, int WPR) {
    const int bid = blockIdx.x;
    const int tid = threadIdx.x;
    const int lane = tid & 63;

    if (bid < CBLKS) {   // ---- compress role: 102 MB label stream -> 3.2 MB raw posmask
        int row = bid / CBPR;
        int sub = bid - row * CBPR;
        int wl  = tid >> 6;
        int w0col = (sub * 4 + wl) * 2048;     // this wave's 2048-col window
        if (w0col >= C) return;
        const int* lp = label + (size_t)row * C;
        intx4 lo[4], hi[4];
        #pragma unroll
        for (int r = 0; r < 4; ++r) {          // 8 x 16B nt loads in flight
            int c0 = w0col + r * 512 + lane * 8;
            if (c0 < C) {                      // C%8==0: full 8-col chunk valid
                lo[r] = __builtin_nontemporal_load((const intx4*)(lp + c0));
                hi[r] = __builtin_nontemporal_load((const intx4*)(lp + c0 + 4));
            } else {
                lo[r] = (intx4)0;
                hi[r] = (intx4)0;
            }
        }
        #pragma unroll
        for (int r = 0; r < 4; ++r) {
            unsigned int by =
                (lo[r][0] ? 1u : 0u) | (lo[r][1] ? 2u : 0u) |
                (lo[r][2] ? 4u : 0u) | (lo[r][3] ? 8u : 0u) |
                (hi[r][0] ? 16u : 0u) | (hi[r][1] ? 32u : 0u) |
                (hi[r][2] ? 64u : 0u) | (hi[r][3] ? 128u : 0u);
            u64 wv = (u64)by << (8 * (lane & 7));
            wv |= __shfl_xor(wv, 1);           // OR-butterfly across 8-lane group
            wv |= __shfl_xor(wv, 2);
            wv |= __shfl_xor(wv, 4);
            if ((lane & 7) == 0) {
                int wc = ((w0col + r * 512) >> 6) + (lane >> 3);
                if (wc < WPR) posmask[(size_t)row * WPR + wc] = wv;
            }
        }
        return;
    }

    // ---- prep role: loadedmask (binary search over sorted ids) + normalize -> bf16
    int ptid = (bid - CBLKS) * 256 + tid;
    if (ptid == 0) { *gcount = 0u; *gaccum = 0.f; }   // zero reduce scratch each call
    if (ptid < WPR) {
        int base = ptid << 6;
        int lo = 0, hi = n_loaded;
        while (lo < hi) { int mid = (lo + hi) >> 1; if (ids[mid] < base) lo = mid + 1; else hi = mid; }
        u64 m = 0;
        for (int i = lo; i < n_loaded; ++i) {
            int v = ids[i]; if (v >= base + 64) break;
            m |= 1ull << (v - base);
        }
        loadedmask[ptid] = m;
    }
    int wave = ptid >> 6;
    if (wave >= B + C) return;   // whole wave uniform
    bool isV = wave < B;
    const float* src = isV ? (V + (size_t)wave * D_DIM)
                           : (T + (size_t)(wave - B) * D_DIM);
    floatx4 x = __builtin_nontemporal_load(((const floatx4*)src) + lane);
    float ss = x[0] * x[0] + x[1] * x[1] + x[2] * x[2] + x[3] * x[3];
    #pragma unroll
    for (int off = 32; off > 0; off >>= 1) ss += __shfl_xor(ss, off);
    float nrm = sqrtf(ss);
    float s = isV ? (1.0f / nrm) : (1.0f / (1e-6f + nrm));   // eps on text norms only
    ushort4 o;
    o.x = f2bf(x[0] * s); o.y = f2bf(x[1] * s);
    o.z = f2bf(x[2] * s); o.w = f2bf(x[3] * s);
    unsigned short* dst = isV ? (Vb + (size_t)wave * D_DIM)
                              : (Tb + (size_t)(wave - B) * D_DIM);
    ((ushort4*)dst)[lane] = o;   // cached store: Vb/Tb are re-read by gemm
}

// ---- kernel 2 (R18): R15 gemm (LDS staging + XCD swizzle) + PRELOADED posmask -------
// R17 ablation: zero-LDS direct-load variant was SLOWER (68.7 vs ~55-62) despite
// FETCH 54->15.5MB -- coalesced gload16 staging wins on issue efficiency; the 1.6M
// "bank conflicts" were gload16 multi-beat accounting (R17: 0 without LDS). Kept: LDS
// staging. New: the 16 serialized wave-uniform posmask loads in the epilogue become
// ONE per-lane load ISSUED BEFORE THE K-LOOP (VMEM idle there; latency fully hidden);
// epilogue reads row rloc's word via __shfl(praw, rloc) -- the R8/R12-verified form.
__global__ __launch_bounds__(256) void gemm_fused(
    const unsigned short* __restrict__ Vb, const unsigned short* __restrict__ Tb,
    const u64* __restrict__ posmask, const u64* __restrict__ loadedmask,
    float* __restrict__ denomP, float* __restrict__ posP, int C, int WPR) {
    __shared__ unsigned short As[2][TM * BK];   // 2 x 8 KB double buffer
    __shared__ unsigned short Bs[2][TN * BK];   // 2 x 8 KB
    __shared__ float sDen[TM], sPos[TM];

    const int tid  = threadIdx.x;
    const int lane = tid & 63;
    const int w    = tid >> 6;

    // bijective XCD-chunk swizzle (R15 win): id%8 = XCD; contiguous wgid chunk per XCD
    const int nwg  = gridDim.x;
    const int id   = blockIdx.x;
    const int q    = nwg >> 3, r = nwg & 7;
    const int xcd  = id & 7, slot = id >> 3;
    const int wgid = (xcd < r) ? xcd * (q + 1) + slot
                               : r * (q + 1) + (xcd - r) * q + slot;
    const int m0 = (wgid & 3) * TM;     // m fastest within the chunk
    const int nb = wgid >> 2;           // n-block index
    const int n0 = nb * TN;

    if (tid < TM) { sDen[tid] = 0.f; sPos[tid] = 0.f; }

    // ---- compute mapping: 2x2 waves, each 64x64 via 4x4 frags of 16x16x32
    const int wm = (w >> 1) * 64;
    const int wn = (w & 1) * 64;
    const int fr = lane & 15;
    const int quad = lane >> 4;

    // ---- per-lane posmask preload: row m0+wm+lane's word for this wave's 64 cols.
    // Issued here so its L2/L3 latency hides under the whole K-loop.
    const int wcol = (n0 + wn) >> 6;
    const u64 loadedw = loadedmask[wcol];
    const u64 praw_l = posmask[(size_t)(m0 + wm + lane) * WPR + wcol];

    // ---- async-staging addresses: wave w covers tile rows [w*32, w*32+32)
    const int sra = lane >> 2;          // row within 16-row group
    const int kc  = (lane & 3) * 8;     // 16B k-chunk
    int ga  = m0 + w * 32 + sra;
    int gb0 = n0 + w * 32 + sra;
    int gb1 = gb0 + 16;
    if (gb0 >= C) gb0 = C - 1;          // OOB rows: valid address, masked in epilogue
    if (gb1 >= C) gb1 = C - 1;
    const unsigned short* gA0 = Vb + (size_t)ga * D_DIM + kc;
    const unsigned short* gA1 = gA0 + (size_t)16 * D_DIM;
    const unsigned short* gB0 = Tb + (size_t)gb0 * D_DIM + kc;
    const unsigned short* gB1 = Tb + (size_t)gb1 * D_DIM + kc;
    const int lofsA = w * 32 * BK;      // wave-uniform LDS offsets (elements)
    const int lofsB = w * 32 * BK;

    floatx4 acc[4][4];
    #pragma unroll
    for (int mi = 0; mi < 4; mi++)
        #pragma unroll
        for (int ni = 0; ni < 4; ni++) acc[mi][ni] = (floatx4)0.f;

    // prologue: stage tile 0 into buffer 0, drain, barrier
    gload16(gA0, &As[0][lofsA]);
    gload16(gA1, &As[0][lofsA + 16 * BK]);
    gload16(gB0, &Bs[0][lofsB]);
    gload16(gB1, &Bs[0][lofsB + 16 * BK]);
    __syncthreads();

    #pragma unroll
    for (int kt = 0; kt < D_DIM / BK; ++kt) {
        const int cur = kt & 1;          // compile-time under full unroll
        if (kt < D_DIM / BK - 1) {       // stage NEXT tile into the other buffer
            const int kb = (kt + 1) * BK;
            gload16(gA0 + kb, &As[cur ^ 1][lofsA]);
            gload16(gA1 + kb, &As[cur ^ 1][lofsA + 16 * BK]);
            gload16(gB0 + kb, &Bs[cur ^ 1][lofsB]);
            gload16(gB1 + kb, &Bs[cur ^ 1][lofsB + 16 * BK]);
        }
        short8 af[4], bf[4];
        #pragma unroll
        for (int mi = 0; mi < 4; mi++)
            af[mi] = *(const short8*)&As[cur][(wm + mi * 16 + fr) * BK + quad * 8];
        #pragma unroll
        for (int ni = 0; ni < 4; ni++)
            bf[ni] = *(const short8*)&Bs[cur][(wn + ni * 16 + fr) * BK + quad * 8];
        #pragma unroll
        for (int mi = 0; mi < 4; mi++)
            #pragma unroll
            for (int ni = 0; ni < 4; ni++)
                acc[mi][ni] = __builtin_amdgcn_mfma_f32_16x16x32_bf16(
                    af[mi], bf[ni], acc[mi][ni], 0, 0, 0);
        __syncthreads();                 // drains this step's stage; swap point
    }

    // ---- epilogue: D layout row = quad*4 + reg, col = lane&15 per 16x16 frag.
    #pragma unroll
    for (int mi = 0; mi < 4; mi++) {
        #pragma unroll
        for (int i = 0; i < 4; i++) {
            const int rloc = mi * 16 + quad * 4 + i;
            const int mloc = wm + rloc;
            const u64 praw = __shfl(praw_l, rloc);   // row rloc's word (R8-verified)
            const u64 posw = praw & loadedw;
            const u64 negw = loadedw & ~praw;
            float den = 0.f, pos = 0.f;
            #pragma unroll
            for (int ni = 0; ni < 4; ni++) {
                const float s = acc[mi][ni][i];
                const int bit = ni * 16 + fr;
                if ((negw >> bit) & 1) den += __expf(s);
                if ((posw >> bit) & 1) pos += s;
            }
            #pragma unroll
            for (int off = 8; off >= 1; off >>= 1) {   // reduce 16-lane quad row
                den += __shfl_xor(den, off);
                pos += __shfl_xor(pos, off);
            }
            if (fr == 0) {
                if (den != 0.f) atomicAdd(&sDen[mloc], den);
                if (pos != 0.f) atomicAdd(&sPos[mloc], pos);
            }
        }
    }
    __syncthreads();
    if (tid < TM) {   // row-major partials: [row][n-block] for coalesced reduce
        denomP[(size_t)(m0 + tid) * NBP + nb] = sDen[tid];
        posP[(size_t)(m0 + tid) * NBP + nb]   = sPos[tid];
    }
}

// ---- kernel 3: reduce rows + last-block computes the final mean (R5-exact) ----------
__global__ void reduce_rows(const float* __restrict__ denomP, const float* __restrict__ posP,
                            const u64* __restrict__ posmask, const u64* __restrict__ loadedmask,
                            float* __restrict__ gaccum, unsigned int* __restrict__ gcount,
                            float* __restrict__ out, int B, int NB, int WPR) {
    __shared__ float bsum[4];
    int wv   = threadIdx.x >> 6;
    int row  = blockIdx.x * 4 + wv;
    int lane = threadIdx.x & 63;
    float den = 0.f, pos = 0.f;
    int cnt = 0;
    if (row < B) {
        for (int bn = lane; bn < NB; bn += 64) {   // contiguous within row: coalesced
            den += denomP[(size_t)row * NBP + bn];
            pos += posP[(size_t)row * NBP + bn];
        }
        for (int j = lane; j < WPR; j += 64)
            cnt += __popcll(posmask[(size_t)row * WPR + j] & loadedmask[j]);
        #pragma unroll
        for (int off = 32; off > 0; off >>= 1) {
            den += __shfl_xor(den, off);
            pos += __shfl_xor(pos, off);
            cnt += __shfl_xor(cnt, off);
        }
    }
    if (lane == 0) bsum[wv] = (row < B) ? (logf(den) - pos / (float)cnt) : 0.f;
    __syncthreads();
    if (threadIdx.x == 0) {
        float s = bsum[0] + bsum[1] + bsum[2] + bsum[3];
        atomicAdd(gaccum, s);            // 128 ops total: contention negligible
        __threadfence();
        unsigned int old = atomicAdd(gcount, 1u);
        if (old == gridDim.x - 1) {      // last block: all adds complete & visible
            float tot = atomicAdd(gaccum, 0.0f);   // atomic read-back
            out[0] = tot / (float)B;
        }
    }
}

extern "C" void kernel_launch(void* const* d_in, const int* in_sizes, int n_in,
                              void* d_out, int out_size, void* d_ws, size_t ws_size,
                              hipStream_t stream) {
    const float* V     = (const float*)d_in[0];
    const float* T     = (const float*)d_in[1];
    const int*   label = (const int*)d_in[2];
    const int*   ids   = (const int*)d_in[3];
    int B = in_sizes[0] / D_DIM;   // 512
    int C = in_sizes[1] / D_DIM;   // 50000
    int n_loaded = in_sizes[3];    // 40000
    int WPR = (C + 63) >> 6;       // mask words per row (782)
    int NB  = (C + TN - 1) / TN;   // n-blocks (391)

    // ws layout (bytes):
    //   0        : gaccum [1 f], gcount [1 u32]     (pad to 2048)
    //   2048     : loadedmask [782 u64]             (ends 8304; pad to 8320)
    //   8320     : posmask [512*782 u64]            (3,203,072 -> ends 3,211,392)
    //   3211392  : Vb [512*256 bf16]                (262,144 -> ends 3,473,536)
    //   3473536  : Tb [50000*256 bf16]              (25.6 MB -> ends 29,073,536)
    //   29073536 : denomP [512*NBP f]               (802,816 -> ends 29,876,352)
    //   29876352 : posP                             (ends 30,679,168)
    char* ws = (char*)d_ws;
    float*        gaccum = (float*)(ws + 0);
    unsigned int* gcount = (unsigned int*)(ws + 8);
    u64*   loadedmask = (u64*)(ws + 2048);
    u64*   posmask    = (u64*)(ws + 8320);
    unsigned short* Vb = (unsigned short*)(ws + 3211392);
    unsigned short* Tb = (unsigned short*)(ws + 3473536);
    float* denomP  = (float*)(ws + 29073536);
    float* posP    = (float*)(ws + 29876352);

    int prep_blocks = ((B + C) * 64 + 255) / 256;    // 12628
    prep_compress<<<CBLKS + prep_blocks, 256, 0, stream>>>(
        V, T, label, ids, loadedmask, posmask, Vb, Tb, gaccum, gcount,
        B, C, n_loaded, WPR);

    int gemm_blocks = (B / TM) * NB;   // 1564; 1D grid for the XCD swizzle
    gemm_fused<<<gemm_blocks, 256, 0, stream>>>(Vb, Tb, posmask, loadedmask,
                                                denomP, posP, C, WPR);

    reduce_rows<<<(B + 3) / 4, 256, 0, stream>>>(denomP, posP, posmask, loadedmask,
                                                 gaccum, gcount, (float*)d_out, B, NB, WPR);
}